// Round 1
// baseline (363.342 us; speedup 1.0000x reference)
//
#include <hip/hip_runtime.h>

typedef __attribute__((ext_vector_type(8))) short bf16x8;
typedef __attribute__((ext_vector_type(4))) float f32x4;

#define N_NODES 8192
#define D_IN    256
#define D_OUT   128

__device__ __forceinline__ unsigned short bf16_rne(float f) {
  unsigned int u = __float_as_uint(f);
  u += 0x7fffu + ((u >> 16) & 1u);
  return (unsigned short)(u >> 16);
}
__device__ __forceinline__ float bf16_to_f(unsigned short s) {
  return __uint_as_float(((unsigned int)s) << 16);
}

// ---------------- k0a: split x (fp32) -> x_hi, x_lo (bf16) ----------------
__global__ __launch_bounds__(256) void k_split_x(const float* __restrict__ x,
                                                 unsigned short* __restrict__ xhi,
                                                 unsigned short* __restrict__ xlo) {
  int idx = (blockIdx.x * 256 + threadIdx.x) * 8;  // 8192*256 / 8 / 256 = 1024 blocks
  float4 v0 = *(const float4*)(x + idx);
  float4 v1 = *(const float4*)(x + idx + 4);
  float v[8] = {v0.x, v0.y, v0.z, v0.w, v1.x, v1.y, v1.z, v1.w};
  unsigned int hw[4], lw[4];
#pragma unroll
  for (int p = 0; p < 4; ++p) {
    unsigned short h0 = bf16_rne(v[2 * p]);
    unsigned short h1 = bf16_rne(v[2 * p + 1]);
    unsigned short l0 = bf16_rne(v[2 * p] - bf16_to_f(h0));
    unsigned short l1 = bf16_rne(v[2 * p + 1] - bf16_to_f(h1));
    hw[p] = (unsigned int)h0 | ((unsigned int)h1 << 16);
    lw[p] = (unsigned int)l0 | ((unsigned int)l1 << 16);
  }
  *(uint4*)(xhi + idx) = make_uint4(hw[0], hw[1], hw[2], hw[3]);
  *(uint4*)(xlo + idx) = make_uint4(lw[0], lw[1], lw[2], lw[3]);
}

// ------------- k0b: split + transpose W -> W_hiT, W_loT [128][256] -------------
__global__ __launch_bounds__(256) void k_split_w(const float* __restrict__ W,
                                                 unsigned short* __restrict__ whiT,
                                                 unsigned short* __restrict__ wloT) {
  int c = blockIdx.x;      // 0..127
  int k = threadIdx.x;     // 0..255
  float v = W[k * D_OUT + c];
  unsigned short h = bf16_rne(v);
  unsigned short l = bf16_rne(v - bf16_to_f(h));
  whiT[c * D_IN + k] = h;
  wloT[c * D_IN + k] = l;
}

// ---------------- k1: h = x @ W  (split-bf16 MFMA, near-fp32) ----------------
// grid 256 blocks (32 rows each), 256 threads = 4 waves.
// wave: m = wv>>1 (16-row frag), nh = wv&1 (64-col half -> 4 n-frags)
__global__ __launch_bounds__(256) void k_h_gemm(const unsigned short* __restrict__ xhi,
                                                const unsigned short* __restrict__ xlo,
                                                const unsigned short* __restrict__ whiT,
                                                const unsigned short* __restrict__ wloT,
                                                float* __restrict__ h) {
  const int t = threadIdx.x, l = t & 63, wv = t >> 6;
  const int i0 = blockIdx.x * 32;
  const int m = wv >> 1, nh = wv & 1;
  const int frow = l & 15, kq = l >> 4;
  const size_t arow = (size_t)(i0 + m * 16 + frow);
  const unsigned short* pah = xhi + arow * D_IN + kq * 8;
  const unsigned short* pal = xlo + arow * D_IN + kq * 8;
  f32x4 acc[4];
#pragma unroll
  for (int nf = 0; nf < 4; ++nf) acc[nf] = (f32x4){0.f, 0.f, 0.f, 0.f};
#pragma unroll
  for (int kk = 0; kk < 8; ++kk) {
    const int k0 = kk * 32;
    bf16x8 ah = *(const bf16x8*)(pah + k0);
    bf16x8 al = *(const bf16x8*)(pal + k0);
#pragma unroll
    for (int nf = 0; nf < 4; ++nf) {
      const int col = nh * 64 + nf * 16 + frow;
      bf16x8 bh = *(const bf16x8*)(whiT + (size_t)col * D_IN + k0 + kq * 8);
      bf16x8 bl = *(const bf16x8*)(wloT + (size_t)col * D_IN + k0 + kq * 8);
      acc[nf] = __builtin_amdgcn_mfma_f32_16x16x32_bf16(ah, bh, acc[nf], 0, 0, 0);
      acc[nf] = __builtin_amdgcn_mfma_f32_16x16x32_bf16(al, bh, acc[nf], 0, 0, 0);
      acc[nf] = __builtin_amdgcn_mfma_f32_16x16x32_bf16(ah, bl, acc[nf], 0, 0, 0);
    }
  }
#pragma unroll
  for (int nf = 0; nf < 4; ++nf) {
#pragma unroll
    for (int r = 0; r < 4; ++r) {
      const int row = i0 + m * 16 + kq * 4 + r;
      h[(size_t)row * D_OUT + nh * 64 + nf * 16 + frow] = acc[nf][r];
    }
  }
}

// ------- k2a: transpose h -> hT_hi, hT_lo [128][8192] bf16 (hi/lo split) -------
// grid 128 blocks (64-row slab), 256 threads: c = t>>1, half = t&1
__global__ __launch_bounds__(256) void k_transpose_h(const float* __restrict__ h,
                                                     unsigned short* __restrict__ hThi,
                                                     unsigned short* __restrict__ hTlo) {
  const int t = threadIdx.x;
  const int r0 = blockIdx.x * 64;
  const int c = t >> 1, half = t & 1;
  unsigned int hw[16], lw[16];
#pragma unroll
  for (int p = 0; p < 16; ++p) {
    float v0 = h[(size_t)(r0 + half * 32 + 2 * p) * D_OUT + c];
    float v1 = h[(size_t)(r0 + half * 32 + 2 * p + 1) * D_OUT + c];
    unsigned short h0 = bf16_rne(v0), h1 = bf16_rne(v1);
    unsigned short l0 = bf16_rne(v0 - bf16_to_f(h0));
    unsigned short l1 = bf16_rne(v1 - bf16_to_f(h1));
    hw[p] = (unsigned int)h0 | ((unsigned int)h1 << 16);
    lw[p] = (unsigned int)l0 | ((unsigned int)l1 << 16);
  }
  const size_t off = (size_t)c * N_NODES + r0 + half * 32;
  uint4* ph = (uint4*)(hThi + off);
  uint4* pl = (uint4*)(hTlo + off);
#pragma unroll
  for (int p = 0; p < 4; ++p) {
    ph[p] = make_uint4(hw[4 * p], hw[4 * p + 1], hw[4 * p + 2], hw[4 * p + 3]);
    pl[p] = make_uint4(lw[4 * p], lw[4 * p + 1], lw[4 * p + 2], lw[4 * p + 3]);
  }
}

// ---------------- k2b: src = h@a_src, dst = h@a_dst (fp32) ----------------
__global__ __launch_bounds__(256) void k_src_dst(const float* __restrict__ h,
                                                 const float* __restrict__ a_src,
                                                 const float* __restrict__ a_dst,
                                                 float* __restrict__ srcv,
                                                 float* __restrict__ dstv) {
  const int row = blockIdx.x * 256 + threadIdx.x;  // grid 32
  const float4* hr = (const float4*)(h + (size_t)row * D_OUT);
  float s = 0.f, d = 0.f;
#pragma unroll
  for (int p = 0; p < 32; ++p) {
    float4 hv = hr[p];
    float4 as = ((const float4*)a_src)[p];
    float4 ad = ((const float4*)a_dst)[p];
    s += hv.x * as.x + hv.y * as.y + hv.z * as.z + hv.w * as.w;
    d += hv.x * ad.x + hv.y * ad.y + hv.z * ad.z + hv.w * ad.w;
  }
  srcv[row] = s;
  dstv[row] = d;
}

// ---------------- k3: fused masked-softmax aggregation ----------------
// grid 256 blocks (32 rows), 1024 threads = 16 waves.
// wave wv: m = wv>>3 (16-row frag), ncb = (wv&7)*16 (16-col frag). BK = 64.
// w-tile: [32 rows][64 j] bf16, double-buffered, XOR-swizzled (byte ^= (row&7)<<4).
__global__ __launch_bounds__(1024) void k_gat(const int* __restrict__ adj,
                                              const float* __restrict__ srcv,
                                              const float* __restrict__ dstv,
                                              const unsigned short* __restrict__ hThi,
                                              const unsigned short* __restrict__ hTlo,
                                              float* __restrict__ out) {
  __shared__ alignas(16) char wt[2][4096];
  __shared__ float rowsum[32];

  const int t = threadIdx.x;
  const int l = t & 63, wv = t >> 6;
  const int i0 = blockIdx.x * 32;

  // w-producer mapping: each thread owns row irow, 2 consecutive j per iter
  const int irow = t >> 5;         // 0..31
  const int j2 = t & 31;           // j pair index within the 64-wide tile
  const float src_i = srcv[i0 + irow];
  const long long* adjrow = (const long long*)(adj + (size_t)(i0 + irow) * N_NODES) + j2;
  const int wbyte = (irow * 128 + j2 * 4) ^ ((irow & 7) << 4);

  // MFMA fragment mapping
  const int m = wv >> 3;
  const int ncb = (wv & 7) * 16;
  const int frow = l & 15, kq = l >> 4;
  const int arow = m * 16 + frow;
  const int abase = arow * 128 + kq * 16;      // bytes, pre-swizzle
  const int aswz = (arow & 7) << 4;
  const unsigned short* bhi = hThi + (size_t)(ncb + frow) * N_NODES + kq * 8;
  const unsigned short* blo = hTlo + (size_t)(ncb + frow) * N_NODES + kq * 8;

  f32x4 acc = {0.f, 0.f, 0.f, 0.f};
  float rs = 0.f;

  long long adjv = __builtin_nontemporal_load(adjrow);
  for (int it = 0; it < 128; ++it) {
    const int j0 = it * 64;
    long long adjn = 0;
    if (it < 127) adjn = __builtin_nontemporal_load(adjrow + (it + 1) * 32);

    // ---- produce w tile (fp32 math, bf16 pack) ----
    float2 dv = *(const float2*)(dstv + j0 + j2 * 2);
    float e0 = src_i + dv.x; e0 = fmaxf(e0, 0.2f * e0);
    float e1 = src_i + dv.y; e1 = fmaxf(e1, 0.2f * e1);
    float w0 = ((int)adjv) > 0 ? __expf(e0) : 0.f;
    float w1 = ((int)(adjv >> 32)) > 0 ? __expf(e1) : 0.f;
    rs += w0 + w1;
    unsigned int pk = (unsigned int)bf16_rne(w0) | ((unsigned int)bf16_rne(w1) << 16);
    *(unsigned int*)(&wt[it & 1][wbyte]) = pk;

    __syncthreads();  // single barrier per iter: double buffer makes it sufficient

    const char* wb = wt[it & 1];
#pragma unroll
    for (int s = 0; s < 2; ++s) {
      bf16x8 a = *(const bf16x8*)(wb + ((abase + s * 64) ^ aswz));
      bf16x8 bh = *(const bf16x8*)(bhi + j0 + s * 32);
      bf16x8 bl = *(const bf16x8*)(blo + j0 + s * 32);
      acc = __builtin_amdgcn_mfma_f32_16x16x32_bf16(a, bh, acc, 0, 0, 0);
      acc = __builtin_amdgcn_mfma_f32_16x16x32_bf16(a, bl, acc, 0, 0, 0);
    }
    adjv = adjn;
  }

  // ---- row sums: reduce across the 32 producer threads per row ----
#pragma unroll
  for (int off = 1; off <= 16; off <<= 1) rs += __shfl_xor(rs, off);
  if ((l & 31) == 0) rowsum[irow] = rs;
  __syncthreads();

  // ---- epilogue: out[i][c] = acc / rowsum ----
  const int col = ncb + frow;
#pragma unroll
  for (int r = 0; r < 4; ++r) {
    const int row = m * 16 + kq * 4 + r;
    out[(size_t)(i0 + row) * D_OUT + col] = acc[r] / rowsum[row];
  }
}

extern "C" void kernel_launch(void* const* d_in, const int* in_sizes, int n_in,
                              void* d_out, int out_size, void* d_ws, size_t ws_size,
                              hipStream_t stream) {
  const float* x     = (const float*)d_in[0];
  const int*   adj   = (const int*)d_in[1];
  const float* W     = (const float*)d_in[2];
  const float* a_src = (const float*)d_in[3];
  const float* a_dst = (const float*)d_in[4];
  float* out = (float*)d_out;

  char* ws = (char*)d_ws;
  unsigned short* xhi  = (unsigned short*)(ws);                              // 4 MB
  unsigned short* xlo  = (unsigned short*)(ws + (4 << 20));                  // 4 MB
  unsigned short* whiT = (unsigned short*)(ws + (8 << 20));                  // 64 KB
  unsigned short* wloT = (unsigned short*)(ws + (8 << 20) + (64 << 10));     // 64 KB
  float*          h    = (float*)(ws + (8 << 20) + (128 << 10));             // 4 MB
  unsigned short* hThi = (unsigned short*)(ws + (12 << 20) + (128 << 10));   // 2 MB
  unsigned short* hTlo = (unsigned short*)(ws + (14 << 20) + (128 << 10));   // 2 MB
  float*          srcv = (float*)(ws + (16 << 20) + (128 << 10));            // 32 KB
  float*          dstv = (float*)(ws + (16 << 20) + (160 << 10));            // 32 KB

  k_split_x<<<dim3(1024), dim3(256), 0, stream>>>(x, xhi, xlo);
  k_split_w<<<dim3(128), dim3(256), 0, stream>>>(W, whiT, wloT);
  k_h_gemm<<<dim3(256), dim3(256), 0, stream>>>(xhi, xlo, whiT, wloT, h);
  k_transpose_h<<<dim3(128), dim3(256), 0, stream>>>(h, hThi, hTlo);
  k_src_dst<<<dim3(32), dim3(256), 0, stream>>>(h, a_src, a_dst, srcv, dstv);
  k_gat<<<dim3(256), dim3(1024), 0, stream>>>(adj, srcv, dstv, hThi, hTlo, out);
}